// Round 1
// baseline (711.831 us; speedup 1.0000x reference)
//
#include <hip/hip_runtime.h>

#define TSTEPS 2048
#define BATCH  4096
#define PF     8   // x prefetch depth (steps)

// ---- fast activation helpers (hw v_exp_f32 / v_rcp_f32) -------------------
__device__ __forceinline__ float fexp2(float x){ return __builtin_amdgcn_exp2f(x); }
__device__ __forceinline__ float frcp (float x){ return __builtin_amdgcn_rcpf(x); }
// sigmoid(x) = 1/(1+2^(-x*log2e)) ; saturates correctly: x->+inf ->1, x->-inf ->0
__device__ __forceinline__ float fsig (float x){ return frcp(1.0f + fexp2(-1.442695041f*x)); }
// tanh(x) = 1 - 2/(2^(2x*log2e)+1) ; saturates to +/-1 via inf/rcp
__device__ __forceinline__ float ftanh_(float x){ return 1.0f - 2.0f*frcp(1.0f + fexp2(2.885390082f*x)); }

// ---- quad-lane xor shuffles via DPP quad_perm (VALU speed, no LDS) --------
template<int CTRL>
__device__ __forceinline__ float qp(float v){
  int s = __float_as_int(v);
  return __int_as_float(__builtin_amdgcn_update_dpp(s, s, CTRL, 0xF, 0xF, false));
}
#define QP1(v) qp<0xB1>(v)   // quad_perm [1,0,3,2]  == shfl_xor 1
#define QP2(v) qp<0x4E>(v)   // quad_perm [2,3,0,1]  == shfl_xor 2
#define QP3(v) qp<0x1B>(v)   // quad_perm [3,2,1,0]  == shfl_xor 3

// ===========================================================================
// RNN: h = tanh(Wih x + bih + Whh h + bhh).  Lane j owns h_j.
// Whh is loaded permuted: wh[k] = Whh[j][j^k] so sum_k wh[k]*h_{j^k} = Whh[j]·h
// ===========================================================================
__device__ __forceinline__ void rnn_run(const float4* __restrict__ xq,
                                        float* __restrict__ out,
                                        const float* __restrict__ Wih,
                                        const float* __restrict__ Whh,
                                        const float* __restrict__ bih,
                                        const float* __restrict__ bhh,
                                        int b, int j)
{
  float wi[4], wh[4];
  #pragma unroll
  for (int i=0;i<4;i++) wi[i] = Wih[j*4+i];
  #pragma unroll
  for (int k=0;k<4;k++) wh[k] = Whh[j*4 + (j^k)];
  const float bias = bih[j] + bhh[j];

  const float4* xp = xq + b;
  const float4* pf = xp + (size_t)PF*BATCH;
  float* op = out + (size_t)b*4 + j;

  float h = 0.0f;
  float4 buf[PF];
  #pragma unroll
  for (int k=0;k<PF;k++) buf[k] = xp[(size_t)k*BATCH];

  #define RNN_STEP(xv)                                             \
    {                                                              \
      float h1=QP1(h), h2=QP2(h), h3=QP3(h);                       \
      float a = bias;                                              \
      a = fmaf(wi[0], (xv).x, a); a = fmaf(wi[1], (xv).y, a);      \
      a = fmaf(wi[2], (xv).z, a); a = fmaf(wi[3], (xv).w, a);      \
      a = fmaf(wh[0], h,  a);  a = fmaf(wh[1], h1, a);             \
      a = fmaf(wh[2], h2, a);  a = fmaf(wh[3], h3, a);             \
      h = ftanh_(a);                                               \
      *op = h; op += (size_t)BATCH*4;                              \
    }

  for (int t=0; t<TSTEPS-PF; t+=PF){
    #pragma unroll
    for (int k=0;k<PF;k++){
      float4 xv = buf[k];
      buf[k] = *pf; pf += BATCH;
      RNN_STEP(xv);
    }
  }
  #pragma unroll
  for (int k=0;k<PF;k++){ float4 xv = buf[k]; RNN_STEP(xv); }
  #undef RNN_STEP
}

// ===========================================================================
// LSTM: lane j owns h_j, c_j; handles gate rows {j, 4+j, 8+j, 12+j} = i,f,g,o
// ===========================================================================
__device__ __forceinline__ void lstm_run(const float4* __restrict__ xq,
                                         float* __restrict__ out,
                                         const float* __restrict__ Wih,
                                         const float* __restrict__ Whh,
                                         const float* __restrict__ bih,
                                         const float* __restrict__ bhh,
                                         int b, int j)
{
  float wi[4][4], wh[4][4], bs[4];
  #pragma unroll
  for (int r=0;r<4;r++){
    const int row = r*4 + j;
    #pragma unroll
    for (int i=0;i<4;i++) wi[r][i] = Wih[row*4+i];
    #pragma unroll
    for (int k=0;k<4;k++) wh[r][k] = Whh[row*4 + (j^k)];
    bs[r] = bih[row] + bhh[row];
  }

  const float4* xp = xq + b;
  const float4* pf = xp + (size_t)PF*BATCH;
  float* op = out + (size_t)b*4 + j;

  float h = 0.0f, c = 0.0f;
  float4 buf[PF];
  #pragma unroll
  for (int k=0;k<PF;k++) buf[k] = xp[(size_t)k*BATCH];

  #define LSTM_STEP(xv)                                                  \
    {                                                                    \
      float h1=QP1(h), h2=QP2(h), h3=QP3(h);                             \
      float g0,g1,g2,g3;                                                 \
      { float a=bs[0];                                                   \
        a=fmaf(wi[0][0],(xv).x,a); a=fmaf(wi[0][1],(xv).y,a);            \
        a=fmaf(wi[0][2],(xv).z,a); a=fmaf(wi[0][3],(xv).w,a);            \
        a=fmaf(wh[0][0],h,a);  a=fmaf(wh[0][1],h1,a);                    \
        a=fmaf(wh[0][2],h2,a); a=fmaf(wh[0][3],h3,a); g0=a; }            \
      { float a=bs[1];                                                   \
        a=fmaf(wi[1][0],(xv).x,a); a=fmaf(wi[1][1],(xv).y,a);            \
        a=fmaf(wi[1][2],(xv).z,a); a=fmaf(wi[1][3],(xv).w,a);            \
        a=fmaf(wh[1][0],h,a);  a=fmaf(wh[1][1],h1,a);                    \
        a=fmaf(wh[1][2],h2,a); a=fmaf(wh[1][3],h3,a); g1=a; }            \
      { float a=bs[2];                                                   \
        a=fmaf(wi[2][0],(xv).x,a); a=fmaf(wi[2][1],(xv).y,a);            \
        a=fmaf(wi[2][2],(xv).z,a); a=fmaf(wi[2][3],(xv).w,a);            \
        a=fmaf(wh[2][0],h,a);  a=fmaf(wh[2][1],h1,a);                    \
        a=fmaf(wh[2][2],h2,a); a=fmaf(wh[2][3],h3,a); g2=a; }            \
      { float a=bs[3];                                                   \
        a=fmaf(wi[3][0],(xv).x,a); a=fmaf(wi[3][1],(xv).y,a);            \
        a=fmaf(wi[3][2],(xv).z,a); a=fmaf(wi[3][3],(xv).w,a);            \
        a=fmaf(wh[3][0],h,a);  a=fmaf(wh[3][1],h1,a);                    \
        a=fmaf(wh[3][2],h2,a); a=fmaf(wh[3][3],h3,a); g3=a; }            \
      float ig=fsig(g0), fg=fsig(g1), gg=ftanh_(g2), og=fsig(g3);        \
      c = fmaf(fg, c, ig*gg);                                            \
      h = og * ftanh_(c);                                                \
      *op = h; op += (size_t)BATCH*4;                                    \
    }

  for (int t=0; t<TSTEPS-PF; t+=PF){
    #pragma unroll
    for (int k=0;k<PF;k++){
      float4 xv = buf[k];
      buf[k] = *pf; pf += BATCH;
      LSTM_STEP(xv);
    }
  }
  #pragma unroll
  for (int k=0;k<PF;k++){ float4 xv = buf[k]; LSTM_STEP(xv); }
  #undef LSTM_STEP
}

// ===========================================================================
// GRU: lane j owns h_j; gate rows {j, 4+j, 8+j} = r,z,n
// n-row: bhh must stay inside the r* product: n = tanh(pn + bin + r*(hn + bhn))
// ===========================================================================
__device__ __forceinline__ void gru_run(const float4* __restrict__ xq,
                                        float* __restrict__ out,
                                        const float* __restrict__ Wih,
                                        const float* __restrict__ Whh,
                                        const float* __restrict__ bih,
                                        const float* __restrict__ bhh,
                                        int b, int j)
{
  float wi[3][4], wh[3][4];
  #pragma unroll
  for (int r=0;r<3;r++){
    const int row = r*4 + j;
    #pragma unroll
    for (int i=0;i<4;i++) wi[r][i] = Wih[row*4+i];
    #pragma unroll
    for (int k=0;k<4;k++) wh[r][k] = Whh[row*4 + (j^k)];
  }
  const float bias_r = bih[j]     + bhh[j];
  const float bias_z = bih[4+j]   + bhh[4+j];
  const float bin    = bih[8+j];
  const float bhn    = bhh[8+j];

  const float4* xp = xq + b;
  const float4* pf = xp + (size_t)PF*BATCH;
  float* op = out + (size_t)b*4 + j;

  float h = 0.0f;
  float4 buf[PF];
  #pragma unroll
  for (int k=0;k<PF;k++) buf[k] = xp[(size_t)k*BATCH];

  #define GRU_STEP(xv)                                                   \
    {                                                                    \
      float h1=QP1(h), h2=QP2(h), h3=QP3(h);                             \
      float ar=bias_r, az=bias_z, an=bin, hn=bhn;                        \
      ar=fmaf(wi[0][0],(xv).x,ar); ar=fmaf(wi[0][1],(xv).y,ar);          \
      ar=fmaf(wi[0][2],(xv).z,ar); ar=fmaf(wi[0][3],(xv).w,ar);          \
      ar=fmaf(wh[0][0],h,ar);  ar=fmaf(wh[0][1],h1,ar);                  \
      ar=fmaf(wh[0][2],h2,ar); ar=fmaf(wh[0][3],h3,ar);                  \
      az=fmaf(wi[1][0],(xv).x,az); az=fmaf(wi[1][1],(xv).y,az);          \
      az=fmaf(wi[1][2],(xv).z,az); az=fmaf(wi[1][3],(xv).w,az);          \
      az=fmaf(wh[1][0],h,az);  az=fmaf(wh[1][1],h1,az);                  \
      az=fmaf(wh[1][2],h2,az); az=fmaf(wh[1][3],h3,az);                  \
      an=fmaf(wi[2][0],(xv).x,an); an=fmaf(wi[2][1],(xv).y,an);          \
      an=fmaf(wi[2][2],(xv).z,an); an=fmaf(wi[2][3],(xv).w,an);          \
      hn=fmaf(wh[2][0],h,hn);  hn=fmaf(wh[2][1],h1,hn);                  \
      hn=fmaf(wh[2][2],h2,hn); hn=fmaf(wh[2][3],h3,hn);                  \
      float r = fsig(ar);                                                \
      float z = fsig(az);                                                \
      float n = ftanh_(fmaf(r, hn, an));                                 \
      h = fmaf(z, h - n, n);   /* (1-z)*n + z*h */                       \
      *op = h; op += (size_t)BATCH*4;                                    \
    }

  for (int t=0; t<TSTEPS-PF; t+=PF){
    #pragma unroll
    for (int k=0;k<PF;k++){
      float4 xv = buf[k];
      buf[k] = *pf; pf += BATCH;
      GRU_STEP(xv);
    }
  }
  #pragma unroll
  for (int k=0;k<PF;k++){ float4 xv = buf[k]; GRU_STEP(xv); }
  #undef GRU_STEP
}

// ===========================================================================
// Fused dispatcher: blocks 0-63 RNN, 64-127 LSTM, 128-191 GRU.
// 256 threads/block = 64 batch elems * 4 lanes. All three nets run
// concurrently on disjoint CUs; x (134 MB) is shared via L2/L3.
// ===========================================================================
__global__ void fused_rnn3(const float* __restrict__ x,
                           const float* __restrict__ rWih, const float* __restrict__ rWhh,
                           const float* __restrict__ rbih, const float* __restrict__ rbhh,
                           const float* __restrict__ lWih, const float* __restrict__ lWhh,
                           const float* __restrict__ lbih, const float* __restrict__ lbhh,
                           const float* __restrict__ gWih, const float* __restrict__ gWhh,
                           const float* __restrict__ gbih, const float* __restrict__ gbhh,
                           float* __restrict__ out)
{
  const int lane = threadIdx.x;
  const int j   = lane & 3;        // hidden index owned by this lane
  const int grp = lane >> 2;       // batch sub-index within block
  const int net = blockIdx.x >> 6; // 0=rnn 1=lstm 2=gru  (64 blocks each)
  const int nb  = blockIdx.x & 63;
  const int b   = nb*64 + grp;

  const float4* xq = (const float4*)x;   // x[t][b][0..3] as one float4
  const size_t NOUT = (size_t)TSTEPS * BATCH * 4;

  if (net == 0)      rnn_run (xq, out,          rWih, rWhh, rbih, rbhh, b, j);
  else if (net == 1) lstm_run(xq, out + NOUT,   lWih, lWhh, lbih, lbhh, b, j);
  else               gru_run (xq, out + 2*NOUT, gWih, gWhh, gbih, gbhh, b, j);
}

extern "C" void kernel_launch(void* const* d_in, const int* in_sizes, int n_in,
                              void* d_out, int out_size, void* d_ws, size_t ws_size,
                              hipStream_t stream) {
  const float* x    = (const float*)d_in[0];
  const float* rWih = (const float*)d_in[1];
  const float* rWhh = (const float*)d_in[2];
  const float* rbih = (const float*)d_in[3];
  const float* rbhh = (const float*)d_in[4];
  const float* lWih = (const float*)d_in[5];
  const float* lWhh = (const float*)d_in[6];
  const float* lbih = (const float*)d_in[7];
  const float* lbhh = (const float*)d_in[8];
  const float* gWih = (const float*)d_in[9];
  const float* gWhh = (const float*)d_in[10];
  const float* gbih = (const float*)d_in[11];
  const float* gbhh = (const float*)d_in[12];
  float* out = (float*)d_out;

  // 192 blocks: 64 per network (4096 batch * 4 lanes / 256 threads)
  fused_rnn3<<<dim3(192), dim3(256), 0, stream>>>(
      x, rWih, rWhh, rbih, rbhh, lWih, lWhh, lbih, lbhh,
      gWih, gWhh, gbih, gbhh, out);
}